// Round 5
// baseline (509.946 us; speedup 1.0000x reference)
//
#include <hip/hip_runtime.h>
#include <hip/hip_bf16.h>

// DRew-GIN: N=50000, E=800000, D=128, L=3, NU=1.
// R5: wave-uniform gather (1 row per wave iter, 4B/lane coalesced), CSR buckets
//     padded to x8 with dummy zero-row index -> exact 8-deep load pipeline,
//     no divergence, no remainder masking.

#define NODES 50000
#define EDGES 800000
#define DIM   128
#define ND    ((long)NODES * DIM)
#define NB3   (3 * NODES)          // buckets: d*3 + (k-1)
#define NPART 8
#define PSIZE (NODES / NPART)
#define NSHAD ((long)(NODES + 1) * DIM)   // shadow tensors have a zero row at NODES

typedef __attribute__((ext_vector_type(8))) short  bf16x8;
typedef __attribute__((ext_vector_type(4))) float  f32x4;

#define LDS_STRIDE 136   // bf16 elements; 272B rows

// ---------------------------------------------------------------------------
__global__ __launch_bounds__(256) void convw_kernel(
    const float* __restrict__ Ws, const float* __restrict__ Wk,
    __hip_bfloat16* __restrict__ WT) {
  int m = blockIdx.x;  // 0..11
  const float* src = (m < 3) ? (Ws + (long)m * 16384) : (Wk + (long)(m - 3) * 16384);
  __hip_bfloat16* dst = WT + (long)m * 16384;
  for (int idx = threadIdx.x; idx < 16384; idx += 256) {
    int k = idx >> 7, n = idx & 127;
    dst[n * 128 + k] = __float2bfloat16(src[idx]);
  }
}

// f32 -> bf16 copy (x shadow).
__global__ __launch_bounds__(256) void x2b_kernel(
    const float4* __restrict__ xin, uint2* __restrict__ xbo, long n4) {
  long i = (long)blockIdx.x * 256 + threadIdx.x;
  if (i >= n4) return;
  float4 v = xin[i];
  union { __hip_bfloat16 h[4]; uint2 u; } pk;
  pk.h[0] = __float2bfloat16(v.x); pk.h[1] = __float2bfloat16(v.y);
  pk.h[2] = __float2bfloat16(v.z); pk.h[3] = __float2bfloat16(v.w);
  xbo[i] = pk.u;
}

// Zero the dummy row (index NODES) of the three gather-source shadows.
__global__ __launch_bounds__(256) void zrow_kernel(
    __hip_bfloat16* __restrict__ xb0, __hip_bfloat16* __restrict__ xb1,
    __hip_bfloat16* __restrict__ xb2) {
  int i = threadIdx.x;  // 0..255: 128 bf16 per row, use first 128 threads
  if (i < DIM) {
    xb0[(long)NODES * DIM + i] = __float2bfloat16(0.f);
    xb1[(long)NODES * DIM + i] = __float2bfloat16(0.f);
    xb2[(long)NODES * DIM + i] = __float2bfloat16(0.f);
  }
}

// ---------------------------------------------------------------------------
// CSR build: histogram, 3-phase scan (padded to x8), XCD-partitioned fill.
__global__ __launch_bounds__(256) void hist_kernel(
    const int* __restrict__ ei, const int* __restrict__ attr,
    int* __restrict__ counts, int E) {
  int e = blockIdx.x * 256 + threadIdx.x;
  if (e >= E) return;
  atomicAdd(&counts[ei[E + e] * 3 + (attr[e] - 1)], 1);
}

// scan over PADDED counts pcnt = (cnt+7)&~7.
__global__ __launch_bounds__(256) void scan_a_kernel(
    const int* __restrict__ counts, int* __restrict__ partial,
    int* __restrict__ blocksums, int n) {
  __shared__ int tmp[256];
  int gid = blockIdx.x * 256 + threadIdx.x;
  int v = (gid < n) ? ((counts[gid] + 7) & ~7) : 0;
  tmp[threadIdx.x] = v;
  __syncthreads();
  for (int off = 1; off < 256; off <<= 1) {
    int t = (threadIdx.x >= off) ? tmp[threadIdx.x - off] : 0;
    __syncthreads();
    tmp[threadIdx.x] += t;
    __syncthreads();
  }
  if (gid < n) partial[gid] = tmp[threadIdx.x] - v;
  if (threadIdx.x == 255) blocksums[blockIdx.x] = tmp[255];
}

__global__ __launch_bounds__(256) void scan_b_kernel(int* __restrict__ bs, int nb) {
  __shared__ int tmp[256];
  __shared__ int carry;
  if (threadIdx.x == 0) carry = 0;
  __syncthreads();
  for (int base = 0; base < nb; base += 256) {
    int gid = base + threadIdx.x;
    int v = (gid < nb) ? bs[gid] : 0;
    tmp[threadIdx.x] = v;
    __syncthreads();
    for (int off = 1; off < 256; off <<= 1) {
      int t = (threadIdx.x >= off) ? tmp[threadIdx.x - off] : 0;
      __syncthreads();
      tmp[threadIdx.x] += t;
      __syncthreads();
    }
    if (gid < nb) bs[gid] = tmp[threadIdx.x] - v + carry;
    __syncthreads();
    if (threadIdx.x == 0) carry += tmp[255];
    __syncthreads();
  }
}

// rowptr/cursor = padded exclusive scan; also write the pad slots = NODES.
__global__ __launch_bounds__(256) void scan_c_kernel(
    int* __restrict__ rowptr, int* __restrict__ cursor,
    const int* __restrict__ bs, int* __restrict__ csr, int n) {
  int gid = blockIdx.x * 256 + threadIdx.x;
  if (gid >= n) return;
  int cnt = cursor[gid];                    // real count
  int pcnt = (cnt + 7) & ~7;
  int val = rowptr[gid] + bs[blockIdx.x];   // padded exclusive prefix
  rowptr[gid] = val;
  cursor[gid] = val;
  for (int i = cnt; i < pcnt; ++i) csr[val + i] = NODES;  // dummy zero-row index
  if (gid == n - 1) rowptr[n] = val + pcnt;
}

__global__ __launch_bounds__(256) void fill_kernel(
    const int* __restrict__ ei, const int* __restrict__ attr,
    int* __restrict__ cursor, int* __restrict__ csr_src, int E) {
  int p = blockIdx.x & (NPART - 1);
  int chunk = blockIdx.x >> 3;
  int e = chunk * 256 + threadIdx.x;
  if (e >= E) return;
  int d = ei[E + e];
  int lo = p * PSIZE;
  if (d < lo || d >= lo + PSIZE) return;
  int pos = atomicAdd(&cursor[d * 3 + (attr[e] - 1)], 1);
  csr_src[pos] = ei[e];
}

// ---------------------------------------------------------------------------
// Fused layer. Gather: one row per wave iteration, 4B/lane, width-8 pipeline.
__global__ __launch_bounds__(256, 3) void layer_kernel(
    const float* __restrict__ xt,               // f32 residual source
    const __hip_bfloat16* __restrict__ xbA,     // bf16 shadow of xt
    const __hip_bfloat16* __restrict__ xbB,     // km1=1 source
    const __hip_bfloat16* __restrict__ xbC,     // km1=2 source
    const __hip_bfloat16* __restrict__ WT,
    const float* __restrict__ bs_t,
    const float* __restrict__ bk_t,
    const float* __restrict__ epsp,
    const int* __restrict__ rowptr,
    const int* __restrict__ csr,
    float* __restrict__ xn,                     // f32 out
    __hip_bfloat16* __restrict__ xnb,           // bf16 shadow out
    int t) {
  __shared__ __hip_bfloat16 b_lds[128 * LDS_STRIDE];  // 34816 B
  __shared__ __hip_bfloat16 a_lds[64 * LDS_STRIDE];   // 17408 B

  int tid = threadIdx.x;
  long row0 = (long)blockIdx.x * 64;
  int wave = tid >> 6, lane = tid & 63;
  int l15 = lane & 15, q = lane >> 4;

  // ---- stage Ws[t] -> b_lds ----
  {
    const uint4* bsrc = (const uint4*)(WT + (long)t * 16384);
#pragma unroll
    for (int i = 0; i < 8; ++i) {
      int idx = tid + 256 * i;
      int n = idx >> 4, k8 = idx & 15;
      uint4 v = bsrc[idx];
      *(uint4*)(b_lds + n * LDS_STRIDE + k8 * 8) = v;
    }
  }
  // ---- stage xbA tile -> a_lds (bf16 direct) ----
  {
    const uint4* asrc = (const uint4*)xbA;
#pragma unroll
    for (int i = 0; i < 4; ++i) {
      int idx = tid + 256 * i;               // 0..1023
      int r = idx >> 4, c8 = idx & 15;
      long grow = row0 + r;
      uint4 v = make_uint4(0u, 0u, 0u, 0u);
      if (grow < NODES) v = asrc[grow * 16 + c8];
      *(uint4*)(a_lds + r * LDS_STRIDE + c8 * 8) = v;
    }
  }
  __syncthreads();

  f32x4 out[8];
  {
    f32x4 acc[8] = {};
    for (int k0 = 0; k0 < 128; k0 += 32) {
      bf16x8 af = *(const bf16x8*)(a_lds + (wave * 16 + l15) * LDS_STRIDE + k0 + 8 * q);
#pragma unroll
      for (int j = 0; j < 8; ++j) {
        bf16x8 bfr = *(const bf16x8*)(b_lds + (16 * j + l15) * LDS_STRIDE + k0 + 8 * q);
        acc[j] = __builtin_amdgcn_mfma_f32_16x16x32_bf16(af, bfr, acc[j], 0, 0, 0);
      }
    }
    float sc = 1.0f + *epsp;
#pragma unroll
    for (int j = 0; j < 8; ++j) {
      float b = bs_t[16 * j + l15];
#pragma unroll
      for (int r = 0; r < 4; ++r) out[j][r] = sc * fmaxf(acc[j][r] + b, 0.f);
    }
  }

  const __hip_bfloat16* xbs[3] = {xbA, xbB, xbC};
  for (int km1 = 0; km1 <= t; ++km1) {
    __syncthreads();
    // stage Wk[t][km1] -> b_lds
    {
      const uint4* bq = (const uint4*)(WT + (long)(3 + t * 3 + km1) * 16384);
#pragma unroll
      for (int i = 0; i < 8; ++i) {
        int idx = tid + 256 * i;
        int n = idx >> 4, k8 = idx & 15;
        uint4 v = bq[idx];
        *(uint4*)(b_lds + n * LDS_STRIDE + k8 * 8) = v;
      }
    }
    // ---- gather: wave-uniform row; lane owns bytes [lane*4, lane*4+4) of row ----
    {
      const __hip_bfloat16* xb = xbs[km1];
      for (int rr = 0; rr < 16; ++rr) {
        int row = wave * 16 + rr;
        long d = row0 + row;
        float a0 = 0.f, a1 = 0.f;
        if (d < NODES) {                       // wave-uniform branch
          long bno = d * 3 + km1;
          int beg = rowptr[bno], end = rowptr[bno + 1];   // padded: (end-beg)%8==0
          for (int base = beg; base < end; base += 64) {
            int rem = end - base;
            int cnt = rem < 64 ? rem : 64;     // multiple of 8
            int idxv = csr[base + (lane < cnt ? lane : 0)];
            for (int j = 0; j < cnt; j += 8) {
              uint v[8];
#pragma unroll
              for (int u = 0; u < 8; ++u) {
                int s = __shfl(idxv, j + u, 64);
                v[u] = *(const uint*)(xb + (long)s * DIM + lane * 2);
              }
#pragma unroll
              for (int u = 0; u < 8; ++u) {
                a0 += __uint_as_float(v[u] << 16);
                a1 += __uint_as_float(v[u] & 0xffff0000u);
              }
            }
          }
        }
        union { __hip_bfloat16 h[2]; uint u; } pk;
        pk.h[0] = __float2bfloat16(a0);
        pk.h[1] = __float2bfloat16(a1);
        *(uint*)(a_lds + row * LDS_STRIDE + lane * 2) = pk.u;
      }
    }
    __syncthreads();
    f32x4 acc[8] = {};
    for (int k0 = 0; k0 < 128; k0 += 32) {
      bf16x8 af = *(const bf16x8*)(a_lds + (wave * 16 + l15) * LDS_STRIDE + k0 + 8 * q);
#pragma unroll
      for (int j = 0; j < 8; ++j) {
        bf16x8 bfr = *(const bf16x8*)(b_lds + (16 * j + l15) * LDS_STRIDE + k0 + 8 * q);
        acc[j] = __builtin_amdgcn_mfma_f32_16x16x32_bf16(af, bfr, acc[j], 0, 0, 0);
      }
    }
    const float* bb = bk_t + km1 * 128;
#pragma unroll
    for (int j = 0; j < 8; ++j) {
      float b = bb[16 * j + l15];
#pragma unroll
      for (int r = 0; r < 4; ++r) out[j][r] += fmaxf(acc[j][r] + b, 0.f);
    }
  }

  // ---- epilogue: xn = xt + relu(out); xnb = bf16(xn) ----
  long rbase = row0 + wave * 16 + q * 4;
#pragma unroll
  for (int j = 0; j < 8; ++j) {
    int col = 16 * j + l15;
#pragma unroll
    for (int r = 0; r < 4; ++r) {
      long grow = rbase + r;
      if (grow < NODES) {
        float v = xt[grow * DIM + col] + fmaxf(out[j][r], 0.f);
        xn[grow * DIM + col] = v;
        xnb[grow * DIM + col] = __float2bfloat16(v);
      }
    }
  }
}

// ---------------------------------------------------------------------------
extern "C" void kernel_launch(void* const* d_in, const int* in_sizes, int n_in,
                              void* d_out, int out_size, void* d_ws, size_t ws_size,
                              hipStream_t stream) {
  const float* x    = (const float*)d_in[0];
  const int*   ei   = (const int*)d_in[1];
  const int*   attr = (const int*)d_in[2];
  const float* Ws   = (const float*)d_in[3];
  const float* bs   = (const float*)d_in[4];
  const float* Wk   = (const float*)d_in[5];
  const float* bk   = (const float*)d_in[6];
  const float* eps  = (const float*)d_in[7];
  float* out = (float*)d_out;

  char* ws = (char*)d_ws;
  size_t off = 0;
  auto alloc = [&](size_t bytes) { char* p = ws + off; off += (bytes + 255) & ~(size_t)255; return p; };
  float* xs1 = (float*)alloc(ND * 4);
  float* xs2 = (float*)alloc(ND * 4);
  __hip_bfloat16* xb0 = (__hip_bfloat16*)alloc(NSHAD * 2);   // bf16(x) + zero row
  __hip_bfloat16* xb1 = (__hip_bfloat16*)alloc(NSHAD * 2);
  __hip_bfloat16* xb2 = (__hip_bfloat16*)alloc(NSHAD * 2);
  __hip_bfloat16* xb3 = (__hip_bfloat16*)alloc(NSHAD * 2);   // layer-2 shadow sink
  __hip_bfloat16* WT  = (__hip_bfloat16*)alloc(12 * 16384 * 2);
  int* cursor    = (int*)alloc((size_t)NB3 * 4);
  int* rowptr    = (int*)alloc((size_t)(NB3 + 1) * 4);
  int* blocksums = (int*)alloc(1024 * 4);
  int* csr_src   = (int*)alloc((size_t)(EDGES + 8 * NB3) * 4);  // padded

  hipLaunchKernelGGL(convw_kernel, dim3(12), dim3(256), 0, stream, Ws, Wk, WT);
  hipLaunchKernelGGL(x2b_kernel, dim3((int)(ND / 4 / 256)), dim3(256), 0, stream,
                     (const float4*)x, (uint2*)xb0, ND / 4);
  hipLaunchKernelGGL(zrow_kernel, dim3(1), dim3(256), 0, stream, xb0, xb1, xb2);
  hipMemsetAsync(cursor, 0, (size_t)NB3 * 4, stream);
  int egrid  = (EDGES + 255) / 256;
  int sgridA = (NB3 + 255) / 256;
  hipLaunchKernelGGL(hist_kernel, dim3(egrid), dim3(256), 0, stream, ei, attr, cursor, EDGES);
  hipLaunchKernelGGL(scan_a_kernel, dim3(sgridA), dim3(256), 0, stream, cursor, rowptr, blocksums, NB3);
  hipLaunchKernelGGL(scan_b_kernel, dim3(1), dim3(256), 0, stream, blocksums, sgridA);
  hipLaunchKernelGGL(scan_c_kernel, dim3(sgridA), dim3(256), 0, stream, rowptr, cursor, blocksums, csr_src, NB3);
  hipLaunchKernelGGL(fill_kernel, dim3(egrid * NPART), dim3(256), 0, stream, ei, attr, cursor, csr_src, EDGES);

  int ggrid = (NODES + 63) / 64;

  // Layer 0
  hipLaunchKernelGGL(layer_kernel, dim3(ggrid), dim3(256), 0, stream,
                     x, xb0, (const __hip_bfloat16*)nullptr, (const __hip_bfloat16*)nullptr,
                     WT, bs + 0, bk + 0, eps + 0, rowptr, csr_src, xs1, xb1, 0);
  // Layer 1
  hipLaunchKernelGGL(layer_kernel, dim3(ggrid), dim3(256), 0, stream,
                     xs1, xb1, xb0, (const __hip_bfloat16*)nullptr,
                     WT, bs + 128, bk + 3 * 128, eps + 1, rowptr, csr_src, xs2, xb2, 1);
  // Layer 2
  hipLaunchKernelGGL(layer_kernel, dim3(ggrid), dim3(256), 0, stream,
                     xs2, xb2, xb1, xb0,
                     WT, bs + 256, bk + 6 * 128, eps + 2, rowptr, csr_src, out, xb3, 2);
}

// Round 6
// 383.705 us; speedup vs baseline: 1.3290x; 1.3290x over previous
//
#include <hip/hip_runtime.h>
#include <hip/hip_bf16.h>

// DRew-GIN: N=50000, E=800000, D=128, L=3, NU=1.
// R6: R4 gather structure (16-lane groups, uint4 row loads) + CSR pad-to-4
//     (dummy zero-row) -> exact 4-deep load pipeline, no masked index load.

#define NODES 50000
#define EDGES 800000
#define DIM   128
#define ND    ((long)NODES * DIM)
#define NB3   (3 * NODES)          // buckets: d*3 + (k-1)
#define NPART 8
#define PSIZE (NODES / NPART)
#define NSHAD ((long)(NODES + 1) * DIM)   // shadows have a zero row at index NODES

typedef __attribute__((ext_vector_type(8))) short  bf16x8;
typedef __attribute__((ext_vector_type(4))) float  f32x4;

#define LDS_STRIDE 136   // bf16 elements; 272B rows

// ---------------------------------------------------------------------------
__global__ __launch_bounds__(256) void convw_kernel(
    const float* __restrict__ Ws, const float* __restrict__ Wk,
    __hip_bfloat16* __restrict__ WT) {
  int m = blockIdx.x;  // 0..11
  const float* src = (m < 3) ? (Ws + (long)m * 16384) : (Wk + (long)(m - 3) * 16384);
  __hip_bfloat16* dst = WT + (long)m * 16384;
  for (int idx = threadIdx.x; idx < 16384; idx += 256) {
    int k = idx >> 7, n = idx & 127;
    dst[n * 128 + k] = __float2bfloat16(src[idx]);
  }
}

// f32 -> bf16 copy (x shadow).
__global__ __launch_bounds__(256) void x2b_kernel(
    const float4* __restrict__ xin, uint2* __restrict__ xbo, long n4) {
  long i = (long)blockIdx.x * 256 + threadIdx.x;
  if (i >= n4) return;
  float4 v = xin[i];
  union { __hip_bfloat16 h[4]; uint2 u; } pk;
  pk.h[0] = __float2bfloat16(v.x); pk.h[1] = __float2bfloat16(v.y);
  pk.h[2] = __float2bfloat16(v.z); pk.h[3] = __float2bfloat16(v.w);
  xbo[i] = pk.u;
}

// Zero the dummy row (index NODES) of the three gather-source shadows.
__global__ __launch_bounds__(256) void zrow_kernel(
    __hip_bfloat16* __restrict__ xb0, __hip_bfloat16* __restrict__ xb1,
    __hip_bfloat16* __restrict__ xb2) {
  int i = threadIdx.x;
  if (i < DIM) {
    xb0[(long)NODES * DIM + i] = __float2bfloat16(0.f);
    xb1[(long)NODES * DIM + i] = __float2bfloat16(0.f);
    xb2[(long)NODES * DIM + i] = __float2bfloat16(0.f);
  }
}

// ---------------------------------------------------------------------------
// CSR build: histogram, 3-phase scan (padded to x4), XCD-partitioned fill.
__global__ __launch_bounds__(256) void hist_kernel(
    const int* __restrict__ ei, const int* __restrict__ attr,
    int* __restrict__ counts, int E) {
  int e = blockIdx.x * 256 + threadIdx.x;
  if (e >= E) return;
  atomicAdd(&counts[ei[E + e] * 3 + (attr[e] - 1)], 1);
}

// scan over PADDED counts pcnt = (cnt+3)&~3.
__global__ __launch_bounds__(256) void scan_a_kernel(
    const int* __restrict__ counts, int* __restrict__ partial,
    int* __restrict__ blocksums, int n) {
  __shared__ int tmp[256];
  int gid = blockIdx.x * 256 + threadIdx.x;
  int v = (gid < n) ? ((counts[gid] + 3) & ~3) : 0;
  tmp[threadIdx.x] = v;
  __syncthreads();
  for (int off = 1; off < 256; off <<= 1) {
    int t = (threadIdx.x >= off) ? tmp[threadIdx.x - off] : 0;
    __syncthreads();
    tmp[threadIdx.x] += t;
    __syncthreads();
  }
  if (gid < n) partial[gid] = tmp[threadIdx.x] - v;
  if (threadIdx.x == 255) blocksums[blockIdx.x] = tmp[255];
}

__global__ __launch_bounds__(256) void scan_b_kernel(int* __restrict__ bs, int nb) {
  __shared__ int tmp[256];
  __shared__ int carry;
  if (threadIdx.x == 0) carry = 0;
  __syncthreads();
  for (int base = 0; base < nb; base += 256) {
    int gid = base + threadIdx.x;
    int v = (gid < nb) ? bs[gid] : 0;
    tmp[threadIdx.x] = v;
    __syncthreads();
    for (int off = 1; off < 256; off <<= 1) {
      int t = (threadIdx.x >= off) ? tmp[threadIdx.x - off] : 0;
      __syncthreads();
      tmp[threadIdx.x] += t;
      __syncthreads();
    }
    if (gid < nb) bs[gid] = tmp[threadIdx.x] - v + carry;
    __syncthreads();
    if (threadIdx.x == 0) carry += tmp[255];
    __syncthreads();
  }
}

// rowptr/cursor = padded exclusive scan; write pad slots = NODES (dummy row).
__global__ __launch_bounds__(256) void scan_c_kernel(
    int* __restrict__ rowptr, int* __restrict__ cursor,
    const int* __restrict__ bs, int* __restrict__ csr, int n) {
  int gid = blockIdx.x * 256 + threadIdx.x;
  if (gid >= n) return;
  int cnt = cursor[gid];
  int pcnt = (cnt + 3) & ~3;
  int val = rowptr[gid] + bs[blockIdx.x];
  rowptr[gid] = val;
  cursor[gid] = val;
  for (int i = cnt; i < pcnt; ++i) csr[val + i] = NODES;
  if (gid == n - 1) rowptr[n] = val + pcnt;
}

__global__ __launch_bounds__(256) void fill_kernel(
    const int* __restrict__ ei, const int* __restrict__ attr,
    int* __restrict__ cursor, int* __restrict__ csr_src, int E) {
  int p = blockIdx.x & (NPART - 1);
  int chunk = blockIdx.x >> 3;
  int e = chunk * 256 + threadIdx.x;
  if (e >= E) return;
  int d = ei[E + e];
  int lo = p * PSIZE;
  if (d < lo || d >= lo + PSIZE) return;
  int pos = atomicAdd(&cursor[d * 3 + (attr[e] - 1)], 1);
  csr_src[pos] = ei[e];
}

// ---------------------------------------------------------------------------
// Fused layer. Gather: 16 lanes/row (uint4 each), 16 groups x 4 rows, 4-deep.
__global__ __launch_bounds__(256, 3) void layer_kernel(
    const float* __restrict__ xt,               // f32 residual source
    const __hip_bfloat16* __restrict__ xbA,     // bf16 shadow of xt
    const __hip_bfloat16* __restrict__ xbB,     // km1=1 source
    const __hip_bfloat16* __restrict__ xbC,     // km1=2 source
    const __hip_bfloat16* __restrict__ WT,
    const float* __restrict__ bs_t,
    const float* __restrict__ bk_t,
    const float* __restrict__ epsp,
    const int* __restrict__ rowptr,
    const int* __restrict__ csr,
    float* __restrict__ xn,                     // f32 out
    __hip_bfloat16* __restrict__ xnb,           // bf16 shadow out
    int t) {
  __shared__ __hip_bfloat16 b_lds[128 * LDS_STRIDE];  // 34816 B
  __shared__ __hip_bfloat16 a_lds[64 * LDS_STRIDE];   // 17408 B

  int tid = threadIdx.x;
  long row0 = (long)blockIdx.x * 64;
  int wave = tid >> 6, lane = tid & 63;
  int l15 = lane & 15, q = lane >> 4;

  // ---- stage Ws[t] -> b_lds ----
  {
    const uint4* bsrc = (const uint4*)(WT + (long)t * 16384);
#pragma unroll
    for (int i = 0; i < 8; ++i) {
      int idx = tid + 256 * i;
      int n = idx >> 4, k8 = idx & 15;
      uint4 v = bsrc[idx];
      *(uint4*)(b_lds + n * LDS_STRIDE + k8 * 8) = v;
    }
  }
  // ---- stage xbA tile -> a_lds (bf16 direct) ----
  {
    const uint4* asrc = (const uint4*)xbA;
#pragma unroll
    for (int i = 0; i < 4; ++i) {
      int idx = tid + 256 * i;               // 0..1023
      int r = idx >> 4, c8 = idx & 15;
      long grow = row0 + r;
      uint4 v = make_uint4(0u, 0u, 0u, 0u);
      if (grow < NODES) v = asrc[grow * 16 + c8];
      *(uint4*)(a_lds + r * LDS_STRIDE + c8 * 8) = v;
    }
  }
  __syncthreads();

  f32x4 out[8];
  {
    f32x4 acc[8] = {};
    for (int k0 = 0; k0 < 128; k0 += 32) {
      bf16x8 af = *(const bf16x8*)(a_lds + (wave * 16 + l15) * LDS_STRIDE + k0 + 8 * q);
#pragma unroll
      for (int j = 0; j < 8; ++j) {
        bf16x8 bfr = *(const bf16x8*)(b_lds + (16 * j + l15) * LDS_STRIDE + k0 + 8 * q);
        acc[j] = __builtin_amdgcn_mfma_f32_16x16x32_bf16(af, bfr, acc[j], 0, 0, 0);
      }
    }
    float sc = 1.0f + *epsp;
#pragma unroll
    for (int j = 0; j < 8; ++j) {
      float b = bs_t[16 * j + l15];
#pragma unroll
      for (int r = 0; r < 4; ++r) out[j][r] = sc * fmaxf(acc[j][r] + b, 0.f);
    }
  }

  const __hip_bfloat16* xbs[3] = {xbA, xbB, xbC};
  for (int km1 = 0; km1 <= t; ++km1) {
    __syncthreads();
    // stage Wk[t][km1] -> b_lds
    {
      const uint4* bq = (const uint4*)(WT + (long)(3 + t * 3 + km1) * 16384);
#pragma unroll
      for (int i = 0; i < 8; ++i) {
        int idx = tid + 256 * i;
        int n = idx >> 4, k8 = idx & 15;
        uint4 v = bq[idx];
        *(uint4*)(b_lds + n * LDS_STRIDE + k8 * 8) = v;
      }
    }
    // ---- gather: 16 lanes/row, 4 rows/group, exact 4-deep uint4 pipeline ----
    {
      const __hip_bfloat16* xb = xbs[km1];
      int group = tid >> 4, lane16 = tid & 15;
      for (int rr = 0; rr < 4; ++rr) {
        int row = group * 4 + rr;
        long d = row0 + row;
        float a0 = 0.f, a1 = 0.f, a2 = 0.f, a3 = 0.f,
              a4 = 0.f, a5 = 0.f, a6 = 0.f, a7 = 0.f;
        if (d < NODES) {
          long bno = d * 3 + km1;
          int beg = rowptr[bno], end = rowptr[bno + 1];   // (end-beg)%4 == 0
          for (int base = beg; base < end; base += 16) {
            int idxv = csr[base + lane16];      // slack-allocated; OOB lanes unused
            int cnt = end - base; if (cnt > 16) cnt = 16;   // multiple of 4
            for (int j = 0; j < cnt; j += 4) {
              int s0 = __shfl(idxv, j + 0, 16);
              int s1 = __shfl(idxv, j + 1, 16);
              int s2 = __shfl(idxv, j + 2, 16);
              int s3 = __shfl(idxv, j + 3, 16);
              uint4 v0 = *(const uint4*)(xb + (long)s0 * DIM + lane16 * 8);
              uint4 v1 = *(const uint4*)(xb + (long)s1 * DIM + lane16 * 8);
              uint4 v2 = *(const uint4*)(xb + (long)s2 * DIM + lane16 * 8);
              uint4 v3 = *(const uint4*)(xb + (long)s3 * DIM + lane16 * 8);
              a0 += __uint_as_float(v0.x << 16) + __uint_as_float(v1.x << 16)
                  + __uint_as_float(v2.x << 16) + __uint_as_float(v3.x << 16);
              a1 += __uint_as_float(v0.x & 0xffff0000u) + __uint_as_float(v1.x & 0xffff0000u)
                  + __uint_as_float(v2.x & 0xffff0000u) + __uint_as_float(v3.x & 0xffff0000u);
              a2 += __uint_as_float(v0.y << 16) + __uint_as_float(v1.y << 16)
                  + __uint_as_float(v2.y << 16) + __uint_as_float(v3.y << 16);
              a3 += __uint_as_float(v0.y & 0xffff0000u) + __uint_as_float(v1.y & 0xffff0000u)
                  + __uint_as_float(v2.y & 0xffff0000u) + __uint_as_float(v3.y & 0xffff0000u);
              a4 += __uint_as_float(v0.z << 16) + __uint_as_float(v1.z << 16)
                  + __uint_as_float(v2.z << 16) + __uint_as_float(v3.z << 16);
              a5 += __uint_as_float(v0.z & 0xffff0000u) + __uint_as_float(v1.z & 0xffff0000u)
                  + __uint_as_float(v2.z & 0xffff0000u) + __uint_as_float(v3.z & 0xffff0000u);
              a6 += __uint_as_float(v0.w << 16) + __uint_as_float(v1.w << 16)
                  + __uint_as_float(v2.w << 16) + __uint_as_float(v3.w << 16);
              a7 += __uint_as_float(v0.w & 0xffff0000u) + __uint_as_float(v1.w & 0xffff0000u)
                  + __uint_as_float(v2.w & 0xffff0000u) + __uint_as_float(v3.w & 0xffff0000u);
            }
          }
        }
        union { __hip_bfloat16 h[8]; uint4 u; } pk;
        pk.h[0] = __float2bfloat16(a0); pk.h[1] = __float2bfloat16(a1);
        pk.h[2] = __float2bfloat16(a2); pk.h[3] = __float2bfloat16(a3);
        pk.h[4] = __float2bfloat16(a4); pk.h[5] = __float2bfloat16(a5);
        pk.h[6] = __float2bfloat16(a6); pk.h[7] = __float2bfloat16(a7);
        *(uint4*)(a_lds + row * LDS_STRIDE + lane16 * 8) = pk.u;
      }
    }
    __syncthreads();
    f32x4 acc[8] = {};
    for (int k0 = 0; k0 < 128; k0 += 32) {
      bf16x8 af = *(const bf16x8*)(a_lds + (wave * 16 + l15) * LDS_STRIDE + k0 + 8 * q);
#pragma unroll
      for (int j = 0; j < 8; ++j) {
        bf16x8 bfr = *(const bf16x8*)(b_lds + (16 * j + l15) * LDS_STRIDE + k0 + 8 * q);
        acc[j] = __builtin_amdgcn_mfma_f32_16x16x32_bf16(af, bfr, acc[j], 0, 0, 0);
      }
    }
    const float* bb = bk_t + km1 * 128;
#pragma unroll
    for (int j = 0; j < 8; ++j) {
      float b = bb[16 * j + l15];
#pragma unroll
      for (int r = 0; r < 4; ++r) out[j][r] += fmaxf(acc[j][r] + b, 0.f);
    }
  }

  // ---- epilogue: xn = xt + relu(out); xnb = bf16(xn) ----
  long rbase = row0 + wave * 16 + q * 4;
#pragma unroll
  for (int j = 0; j < 8; ++j) {
    int col = 16 * j + l15;
#pragma unroll
    for (int r = 0; r < 4; ++r) {
      long grow = rbase + r;
      if (grow < NODES) {
        float v = xt[grow * DIM + col] + fmaxf(out[j][r], 0.f);
        xn[grow * DIM + col] = v;
        xnb[grow * DIM + col] = __float2bfloat16(v);
      }
    }
  }
}

// ---------------------------------------------------------------------------
extern "C" void kernel_launch(void* const* d_in, const int* in_sizes, int n_in,
                              void* d_out, int out_size, void* d_ws, size_t ws_size,
                              hipStream_t stream) {
  const float* x    = (const float*)d_in[0];
  const int*   ei   = (const int*)d_in[1];
  const int*   attr = (const int*)d_in[2];
  const float* Ws   = (const float*)d_in[3];
  const float* bs   = (const float*)d_in[4];
  const float* Wk   = (const float*)d_in[5];
  const float* bk   = (const float*)d_in[6];
  const float* eps  = (const float*)d_in[7];
  float* out = (float*)d_out;

  char* ws = (char*)d_ws;
  size_t off = 0;
  auto alloc = [&](size_t bytes) { char* p = ws + off; off += (bytes + 255) & ~(size_t)255; return p; };
  float* xs1 = (float*)alloc(ND * 4);
  float* xs2 = (float*)alloc(ND * 4);
  __hip_bfloat16* xb0 = (__hip_bfloat16*)alloc(NSHAD * 2);
  __hip_bfloat16* xb1 = (__hip_bfloat16*)alloc(NSHAD * 2);
  __hip_bfloat16* xb2 = (__hip_bfloat16*)alloc(NSHAD * 2);
  __hip_bfloat16* xb3 = (__hip_bfloat16*)alloc(NSHAD * 2);
  __hip_bfloat16* WT  = (__hip_bfloat16*)alloc(12 * 16384 * 2);
  int* cursor    = (int*)alloc((size_t)NB3 * 4);
  int* rowptr    = (int*)alloc((size_t)(NB3 + 1) * 4);
  int* blocksums = (int*)alloc(1024 * 4);
  int* csr_src   = (int*)alloc((size_t)(EDGES + 4 * NB3 + 16) * 4);  // padded + slack

  hipLaunchKernelGGL(convw_kernel, dim3(12), dim3(256), 0, stream, Ws, Wk, WT);
  hipLaunchKernelGGL(x2b_kernel, dim3((int)(ND / 4 / 256)), dim3(256), 0, stream,
                     (const float4*)x, (uint2*)xb0, ND / 4);
  hipLaunchKernelGGL(zrow_kernel, dim3(1), dim3(256), 0, stream, xb0, xb1, xb2);
  hipMemsetAsync(cursor, 0, (size_t)NB3 * 4, stream);
  int egrid  = (EDGES + 255) / 256;
  int sgridA = (NB3 + 255) / 256;
  hipLaunchKernelGGL(hist_kernel, dim3(egrid), dim3(256), 0, stream, ei, attr, cursor, EDGES);
  hipLaunchKernelGGL(scan_a_kernel, dim3(sgridA), dim3(256), 0, stream, cursor, rowptr, blocksums, NB3);
  hipLaunchKernelGGL(scan_b_kernel, dim3(1), dim3(256), 0, stream, blocksums, sgridA);
  hipLaunchKernelGGL(scan_c_kernel, dim3(sgridA), dim3(256), 0, stream, rowptr, cursor, blocksums, csr_src, NB3);
  hipLaunchKernelGGL(fill_kernel, dim3(egrid * NPART), dim3(256), 0, stream, ei, attr, cursor, csr_src, EDGES);

  int ggrid = (NODES + 63) / 64;

  // Layer 0
  hipLaunchKernelGGL(layer_kernel, dim3(ggrid), dim3(256), 0, stream,
                     x, xb0, (const __hip_bfloat16*)nullptr, (const __hip_bfloat16*)nullptr,
                     WT, bs + 0, bk + 0, eps + 0, rowptr, csr_src, xs1, xb1, 0);
  // Layer 1
  hipLaunchKernelGGL(layer_kernel, dim3(ggrid), dim3(256), 0, stream,
                     xs1, xb1, xb0, (const __hip_bfloat16*)nullptr,
                     WT, bs + 128, bk + 3 * 128, eps + 1, rowptr, csr_src, xs2, xb2, 1);
  // Layer 2
  hipLaunchKernelGGL(layer_kernel, dim3(ggrid), dim3(256), 0, stream,
                     xs2, xb2, xb1, xb0,
                     WT, bs + 256, bk + 6 * 128, eps + 2, rowptr, csr_src, out, xb3, 2);
}